// Round 1
// baseline (152.891 us; speedup 1.0000x reference)
//
#include <hip/hip_runtime.h>

// QueryAndGroup (PointNet++): ball query (R=0.2, nsample=32) + grouping.
// B=4, N=16384, NPOINT=2048, C=64, out = (B, 3+C, NPOINT, NSAMPLE) f32.
//
// One wave (64 lanes) per query point:
//   phase 1: scan xyz in 64-chunks, ballot + prefix-popcount append of in-ball
//            indices (index order == stable argsort semantics), early exit at 32.
//   phase 2: gather 67 channels, 2 channels/iter; each half-wave writes 32
//            contiguous floats (coalesced 128B segments).
//
// d2 computed with __f*_rn intrinsics in the reference's association
// ((dx^2 + dy^2) + dz^2) so no FMA contraction -> bit-identical mask vs numpy.

namespace {
constexpr int kN  = 16384;
constexpr int kNP = 2048;
constexpr int kC  = 64;
constexpr int kNS = 32;
constexpr int kOC = 3 + kC;   // 67
}

__global__ __launch_bounds__(256) void qg_kernel(
    const float* __restrict__ xyz,      // (B, N, 3)
    const float* __restrict__ new_xyz,  // (B, NPOINT, 3)
    const float* __restrict__ feat,     // (B, C, N)
    float* __restrict__ out)            // (B, 67, NPOINT, NSAMPLE)
{
    __shared__ int sIdx[4][kNS];
    const int wave = threadIdx.x >> 6;
    const int lane = threadIdx.x & 63;

    // XCD-aware mapping (blockIdx % 8 -> XCD round-robin assumption, perf-only):
    // XCD pair {2b, 2b+1} handles batch b, so each XCD's L2 caches one batch's
    // features (4 MB) + xyz (192 KB).
    const int bid  = blockIdx.x;            // 0..2047
    const int xcd  = bid & 7;
    const int b    = xcd >> 1;              // 0..3
    const int jblk = ((xcd & 1) << 8) | (bid >> 3);  // 0..511
    const int j    = (jblk << 2) | wave;    // 0..2047

    const float* __restrict__ xb = xyz + (size_t)b * kN * 3;
    const float* nxp = new_xyz + ((size_t)b * kNP + j) * 3;
    const float nx = nxp[0], ny = nxp[1], nz = nxp[2];
    const float R2 = 0.04f;  // f32(0.2*0.2 in f64), matches jax weak-type compare

    // ---- phase 1: ball query ----
    int count = 0;
    for (int base = 0; base < kN; base += 64) {
        const int i = base + lane;
        const float* p = xb + (size_t)i * 3;
        const float dx = __fsub_rn(nx, p[0]);
        const float dy = __fsub_rn(ny, p[1]);
        const float dz = __fsub_rn(nz, p[2]);
        const float d2 =
            __fadd_rn(__fadd_rn(__fmul_rn(dx, dx), __fmul_rn(dy, dy)),
                      __fmul_rn(dz, dz));
        const bool in = d2 < R2;
        const unsigned long long bal = __ballot(in);
        const int pre  = (int)__popcll(bal & ((1ull << lane) - 1ull));
        const int slot = count + pre;
        if (in && slot < kNS) sIdx[wave][slot] = i;
        count += (int)__popcll(bal);
        if (count >= kNS) break;   // wave-uniform (count uniform via ballot)
    }
    __builtin_amdgcn_wave_barrier();

    // fill rule: count==0 -> all 0; else pad tail with first in-ball index
    if (count == 0) {
        if (lane < kNS) sIdx[wave][lane] = 0;
    } else if (count < kNS) {
        const int first = sIdx[wave][0];
        __builtin_amdgcn_wave_barrier();
        if (lane >= count && lane < kNS) sIdx[wave][lane] = first;
    }
    __builtin_amdgcn_wave_barrier();

    // ---- phase 2: gather + write ----
    const int s    = lane & 31;
    const int half = lane >> 5;
    const int id   = sIdx[wave][s];

    // grouped_xyz = xyz[id] - new_xyz[j]  (single subs: exactly rounded)
    const float g0 = xb[(size_t)id * 3 + 0] - nx;
    const float g1 = xb[(size_t)id * 3 + 1] - ny;
    const float g2 = xb[(size_t)id * 3 + 2] - nz;

    const size_t cs = (size_t)kNP * kNS;                     // channel stride
    float* ob = out + (((size_t)b * kOC) * kNP + j) * kNS + s;
    const float* fb = feat + ((size_t)b * kC) * kN + id;

    #pragma unroll
    for (int cb = 0; cb < kOC; cb += 2) {
        const int c = cb + half;
        if (c < kOC) {
            float v;
            if (c < 3) {
                v = (c == 0) ? g0 : ((c == 1) ? g1 : g2);
            } else {
                v = fb[(size_t)(c - 3) * kN];
            }
            ob[(size_t)c * cs] = v;
        }
    }
}

extern "C" void kernel_launch(void* const* d_in, const int* in_sizes, int n_in,
                              void* d_out, int out_size, void* d_ws, size_t ws_size,
                              hipStream_t stream) {
    const float* xyz     = (const float*)d_in[0];
    const float* new_xyz = (const float*)d_in[1];
    const float* feat    = (const float*)d_in[2];
    float* out           = (float*)d_out;
    // 2048 blocks x 256 threads = 8192 waves = one wave per (b, j) query.
    qg_kernel<<<dim3(2048), dim3(256), 0, stream>>>(xyz, new_xyz, feat, out);
}

// Round 2
// 152.597 us; speedup vs baseline: 1.0019x; 1.0019x over previous
//
#include <hip/hip_runtime.h>

// QueryAndGroup (PointNet++): ball query (R=0.2, nsample=32) + grouping.
// B=4, N=16384, NPOINT=2048, C=64, out = (B, 3+C, NPOINT, NSAMPLE) f32.
//
// R2 structure:
//   K1: transpose features (B,C,N) -> ws (B,N,C) so each sample's channels
//       are one contiguous 256B row (kills the 16x L2 line amplification of
//       per-channel 4B gathers).
//   K2: one wave per query. Phase 1: ball query (ballot + prefix-popcount,
//       prefetch-pipelined, early exit at 32 hits). Phase 2: gather 8x float4
//       per lane from transposed rows; stores are dense 128B segments.
//
// d2 uses __f*_rn in the reference's association ((dx^2+dy^2)+dz^2): no FMA
// contraction -> bit-identical mask vs numpy (R1: absmax 0.0).

namespace {
constexpr int kN  = 16384;
constexpr int kNP = 2048;
constexpr int kC  = 64;
constexpr int kNS = 32;
constexpr int kOC = 3 + kC;   // 67
}

// ---------- K1: feature transpose (B,C,N) -> (B,N,C) ----------
__global__ __launch_bounds__(256) void tr_kernel(
    const float* __restrict__ feat, float* __restrict__ tf)
{
    __shared__ float tile[64][65];           // +1 pad: conflict-free both ways
    const int b  = blockIdx.x >> 8;          // 4 batches
    const int n0 = (blockIdx.x & 255) << 6;  // 256 tiles of 64 along N
    const float* fb = feat + (size_t)b * kC * kN;
    float* ob       = tf   + (size_t)b * kN * kC;
    const int t  = threadIdx.x;
    const int q  = t >> 6;    // 0..3
    const int nn = t & 63;
    #pragma unroll
    for (int p = 0; p < 16; ++p) {           // load coalesced along N
        const int c = p * 4 + q;
        tile[c][nn] = fb[(size_t)c * kN + n0 + nn];
    }
    __syncthreads();
    const int cc = t & 63;
    #pragma unroll
    for (int p = 0; p < 16; ++p) {           // store coalesced along C
        const int n = p * 4 + q;
        ob[(size_t)(n0 + n) * kC + cc] = tile[cc][n];
    }
}

// ---------- K2: fused ball query + group (transposed features) ----------
__global__ __launch_bounds__(256) void qg_fused(
    const float* __restrict__ xyz,      // (B, N, 3)
    const float* __restrict__ new_xyz,  // (B, NPOINT, 3)
    const float* __restrict__ tf,       // (B, N, C) transposed features
    float* __restrict__ out)            // (B, 67, NPOINT, NSAMPLE)
{
    __shared__ int sIdx[4][kNS];
    const int wave = threadIdx.x >> 6;
    const int lane = threadIdx.x & 63;

    // XCD-aware mapping: XCD pair {2b,2b+1} -> batch b (L2 locality, perf-only).
    const int bid  = blockIdx.x;
    const int xcd  = bid & 7;
    const int b    = xcd >> 1;
    const int jblk = ((xcd & 1) << 8) | (bid >> 3);
    const int j    = (jblk << 2) | wave;

    const float* __restrict__ xb = xyz + (size_t)b * kN * 3;
    const float* nxp = new_xyz + ((size_t)b * kNP + j) * 3;
    const float nx = nxp[0], ny = nxp[1], nz = nxp[2];
    const float R2 = 0.04f;

    // ---- phase 1: ball query (1-deep prefetch pipeline) ----
    int count = 0;
    float px = xb[(size_t)lane * 3 + 0];
    float py = xb[(size_t)lane * 3 + 1];
    float pz = xb[(size_t)lane * 3 + 2];
    for (int base = 0; base < kN; base += 64) {
        float qx = 0.f, qy = 0.f, qz = 0.f;
        if (base + 64 < kN) {
            const float* pn = xb + (size_t)(base + 64 + lane) * 3;
            qx = pn[0]; qy = pn[1]; qz = pn[2];
        }
        const float dx = __fsub_rn(nx, px);
        const float dy = __fsub_rn(ny, py);
        const float dz = __fsub_rn(nz, pz);
        const float d2 =
            __fadd_rn(__fadd_rn(__fmul_rn(dx, dx), __fmul_rn(dy, dy)),
                      __fmul_rn(dz, dz));
        const unsigned long long bal = __ballot(d2 < R2);
        const int pre  = (int)__popcll(bal & ((1ull << lane) - 1ull));
        const int slot = count + pre;
        if ((d2 < R2) && slot < kNS) sIdx[wave][slot] = base + lane;
        count += (int)__popcll(bal);
        if (count >= kNS) break;   // wave-uniform
        px = qx; py = qy; pz = qz;
    }
    __builtin_amdgcn_wave_barrier();

    if (count == 0) {
        if (lane < kNS) sIdx[wave][lane] = 0;
    } else if (count < kNS) {
        const int first = sIdx[wave][0];
        __builtin_amdgcn_wave_barrier();
        if (lane >= count && lane < kNS) sIdx[wave][lane] = first;
    }
    __builtin_amdgcn_wave_barrier();

    // ---- phase 2: gather + write ----
    const int s = lane & 31;
    const int h = lane >> 5;
    const int id = sIdx[wave][s];

    const size_t cs = (size_t)kNP * kNS;     // out channel stride
    float* ob0 = out + ((size_t)b * kOC * kNP + j) * kNS + s;

    // xyz channels (0..2): half-wave h==0 only; dense 128B per store.
    if (h == 0) {
        const float g0 = xb[(size_t)id * 3 + 0] - nx;
        const float g1 = xb[(size_t)id * 3 + 1] - ny;
        const float g2 = xb[(size_t)id * 3 + 2] - nz;
        ob0[0 * cs] = g0;
        ob0[1 * cs] = g1;
        ob0[2 * cs] = g2;
    }

    // feature channels (3..66): 8 independent float4 gathers per lane.
    const float* row = tf + ((size_t)b * kN + id) * kC;
    float* obf = ob0 + 3 * cs;
    #pragma unroll
    for (int it = 0; it < 8; ++it) {
        const int chunk = it * 2 + h;        // 0..15, full 256B row covered
        const float4 v = *reinterpret_cast<const float4*>(row + chunk * 4);
        const size_t c0 = (size_t)chunk * 4;
        obf[(c0 + 0) * cs] = v.x;
        obf[(c0 + 1) * cs] = v.y;
        obf[(c0 + 2) * cs] = v.z;
        obf[(c0 + 3) * cs] = v.w;
    }
}

// ---------- fallback (R1 kernel): direct gather from (C,N) ----------
__global__ __launch_bounds__(256) void qg_direct(
    const float* __restrict__ xyz, const float* __restrict__ new_xyz,
    const float* __restrict__ feat, float* __restrict__ out)
{
    __shared__ int sIdx[4][kNS];
    const int wave = threadIdx.x >> 6;
    const int lane = threadIdx.x & 63;
    const int bid  = blockIdx.x;
    const int xcd  = bid & 7;
    const int b    = xcd >> 1;
    const int jblk = ((xcd & 1) << 8) | (bid >> 3);
    const int j    = (jblk << 2) | wave;

    const float* __restrict__ xb = xyz + (size_t)b * kN * 3;
    const float* nxp = new_xyz + ((size_t)b * kNP + j) * 3;
    const float nx = nxp[0], ny = nxp[1], nz = nxp[2];
    const float R2 = 0.04f;

    int count = 0;
    for (int base = 0; base < kN; base += 64) {
        const int i = base + lane;
        const float* p = xb + (size_t)i * 3;
        const float dx = __fsub_rn(nx, p[0]);
        const float dy = __fsub_rn(ny, p[1]);
        const float dz = __fsub_rn(nz, p[2]);
        const float d2 =
            __fadd_rn(__fadd_rn(__fmul_rn(dx, dx), __fmul_rn(dy, dy)),
                      __fmul_rn(dz, dz));
        const bool in = d2 < R2;
        const unsigned long long bal = __ballot(in);
        const int pre  = (int)__popcll(bal & ((1ull << lane) - 1ull));
        const int slot = count + pre;
        if (in && slot < kNS) sIdx[wave][slot] = i;
        count += (int)__popcll(bal);
        if (count >= kNS) break;
    }
    __builtin_amdgcn_wave_barrier();
    if (count == 0) {
        if (lane < kNS) sIdx[wave][lane] = 0;
    } else if (count < kNS) {
        const int first = sIdx[wave][0];
        __builtin_amdgcn_wave_barrier();
        if (lane >= count && lane < kNS) sIdx[wave][lane] = first;
    }
    __builtin_amdgcn_wave_barrier();

    const int s    = lane & 31;
    const int half = lane >> 5;
    const int id   = sIdx[wave][s];
    const float g0 = xb[(size_t)id * 3 + 0] - nx;
    const float g1 = xb[(size_t)id * 3 + 1] - ny;
    const float g2 = xb[(size_t)id * 3 + 2] - nz;
    const size_t cs = (size_t)kNP * kNS;
    float* ob = out + (((size_t)b * kOC) * kNP + j) * kNS + s;
    const float* fb = feat + ((size_t)b * kC) * kN + id;
    #pragma unroll
    for (int cb = 0; cb < kOC; cb += 2) {
        const int c = cb + half;
        if (c < kOC) {
            float v;
            if (c < 3) v = (c == 0) ? g0 : ((c == 1) ? g1 : g2);
            else       v = fb[(size_t)(c - 3) * kN];
            ob[(size_t)c * cs] = v;
        }
    }
}

extern "C" void kernel_launch(void* const* d_in, const int* in_sizes, int n_in,
                              void* d_out, int out_size, void* d_ws, size_t ws_size,
                              hipStream_t stream) {
    const float* xyz     = (const float*)d_in[0];
    const float* new_xyz = (const float*)d_in[1];
    const float* feat    = (const float*)d_in[2];
    float* out           = (float*)d_out;

    const size_t need = (size_t)4 * kN * kC * sizeof(float);  // 16.8 MB
    if (ws_size >= need) {
        float* tf = (float*)d_ws;
        tr_kernel<<<dim3(1024), dim3(256), 0, stream>>>(feat, tf);
        qg_fused <<<dim3(2048), dim3(256), 0, stream>>>(xyz, new_xyz, tf, out);
    } else {
        qg_direct<<<dim3(2048), dim3(256), 0, stream>>>(xyz, new_xyz, feat, out);
    }
}

// Round 3
// 107.467 us; speedup vs baseline: 1.4227x; 1.4199x over previous
//
#include <hip/hip_runtime.h>

// QueryAndGroup (PointNet++): ball query (R=0.2, nsample=32) + grouping.
// B=4, N=16384, NPOINT=2048, C=64, out = (B, 3+C, NPOINT, NSAMPLE) f32.
//
// R3 structure:
//   K1: transpose features (B,C,N) -> ws (B,N,C)  (kills gather line ampl.)
//   K2: ONE BLOCK (256 threads) per query.
//       Phase 1: cooperative ball query, 1024 points/window (4/thread,
//       float4 double-buffered). Ordered append via per-wave ballots +
//       lane prefix + block prefix of wave totals. Early exit at >=32 hits.
//       Worst-case 16 windows (was 256 wave-iterations in R2 -> tail fix).
//       Phase 2: 256 threads gather/write: thread (s,g) handles sample s,
//       channel-groups g and g+8 -> dense 128B store segments.
//
// d2 uses __f*_rn in the reference's association ((dx^2+dy^2)+dz^2): no FMA
// contraction -> bit-identical ball mask vs numpy (R1/R2: absmax 0.0).

namespace {
constexpr int kN   = 16384;
constexpr int kNP  = 2048;
constexpr int kC   = 64;
constexpr int kNS  = 32;
constexpr int kOC  = 3 + kC;   // 67
constexpr int kWin = 1024;     // points per cooperative window
}

__device__ __forceinline__ float d2_rn(float nx, float ny, float nz,
                                       float px, float py, float pz) {
    const float dx = __fsub_rn(nx, px);
    const float dy = __fsub_rn(ny, py);
    const float dz = __fsub_rn(nz, pz);
    return __fadd_rn(__fadd_rn(__fmul_rn(dx, dx), __fmul_rn(dy, dy)),
                     __fmul_rn(dz, dz));
}

// ---------- K1: feature transpose (B,C,N) -> (B,N,C) ----------
__global__ __launch_bounds__(256) void tr_kernel(
    const float* __restrict__ feat, float* __restrict__ tf)
{
    __shared__ float tile[64][65];
    const int b  = blockIdx.x >> 8;
    const int n0 = (blockIdx.x & 255) << 6;
    const float* fb = feat + (size_t)b * kC * kN;
    float* ob       = tf   + (size_t)b * kN * kC;
    const int t  = threadIdx.x;
    const int q  = t >> 6;
    const int nn = t & 63;
    #pragma unroll
    for (int p = 0; p < 16; ++p) {
        const int c = p * 4 + q;
        tile[c][nn] = fb[(size_t)c * kN + n0 + nn];
    }
    __syncthreads();
    const int cc = t & 63;
    #pragma unroll
    for (int p = 0; p < 16; ++p) {
        const int n = p * 4 + q;
        ob[(size_t)(n0 + n) * kC + cc] = tile[cc][n];
    }
}

// ---------- K2: fused ball query + group, one block per query ----------
__global__ __launch_bounds__(256) void qg_fused(
    const float* __restrict__ xyz,      // (B, N, 3)
    const float* __restrict__ new_xyz,  // (B, NPOINT, 3)
    const float* __restrict__ tf,       // (B, N, C)
    float* __restrict__ out)            // (B, 67, NPOINT, NSAMPLE)
{
    __shared__ int sIdx[kNS];
    __shared__ int sTot[4];

    const int t = threadIdx.x;          // 0..255
    const int w = t >> 6;               // wave 0..3
    const int l = t & 63;               // lane

    // XCD-aware mapping: XCD pair {2b,2b+1} -> batch b (perf-only).
    const int bid = blockIdx.x;         // 0..8191
    const int xcd = bid & 7;
    const int b   = xcd >> 1;
    const int j   = ((xcd & 1) << 10) | (bid >> 3);   // 0..2047

    const float* __restrict__ xb = xyz + (size_t)b * kN * 3;
    const float4* __restrict__ xv = reinterpret_cast<const float4*>(xb);
    const float* nxp = new_xyz + ((size_t)b * kNP + j) * 3;
    const float nx = nxp[0], ny = nxp[1], nz = nxp[2];
    const float R2 = 0.04f;

    // ---- phase 1: cooperative ball query, 1024-point windows ----
    // thread t covers points base+4t .. base+4t+3 (index order = (w,l,k)).
    int count = 0;
    float4 A0, A1, A2, B0, B1, B2;
    {
        const int o = 3 * t;            // (base=0): float4 idx
        B0 = xv[o]; B1 = xv[o + 1]; B2 = xv[o + 2];
    }
    for (int base = 0; base < kN; base += kWin) {
        A0 = B0; A1 = B1; A2 = B2;
        if (base + kWin < kN) {
            const int o = ((base + kWin) >> 2) * 3 + 3 * t;
            B0 = xv[o]; B1 = xv[o + 1]; B2 = xv[o + 2];
        }
        const float d0 = d2_rn(nx, ny, nz, A0.x, A0.y, A0.z);
        const float d1 = d2_rn(nx, ny, nz, A0.w, A1.x, A1.y);
        const float d2v = d2_rn(nx, ny, nz, A1.z, A1.w, A2.x);
        const float d3 = d2_rn(nx, ny, nz, A2.y, A2.z, A2.w);
        const unsigned long long b0 = __ballot(d0 < R2);
        const unsigned long long b1 = __ballot(d1 < R2);
        const unsigned long long b2 = __ballot(d2v < R2);
        const unsigned long long b3 = __ballot(d3 < R2);

        __syncthreads();   // protect sTot (prev iteration readers done)
        if (l == 0)
            sTot[w] = (int)(__popcll(b0) + __popcll(b1) +
                            __popcll(b2) + __popcll(b3));
        __syncthreads();

        int wbase = count;
        #pragma unroll
        for (int ww = 0; ww < 4; ++ww)
            if (ww < w) wbase += sTot[ww];
        const int wtot = sTot[0] + sTot[1] + sTot[2] + sTot[3];

        const unsigned long long m = (1ull << l) - 1ull;
        int slot = wbase + (int)(__popcll(b0 & m) + __popcll(b1 & m) +
                                 __popcll(b2 & m) + __popcll(b3 & m));
        const int i0 = base + 4 * t;
        if (d0 < R2)  { if (slot < kNS) sIdx[slot] = i0 + 0; ++slot; }
        if (d1 < R2)  { if (slot < kNS) sIdx[slot] = i0 + 1; ++slot; }
        if (d2v < R2) { if (slot < kNS) sIdx[slot] = i0 + 2; ++slot; }
        if (d3 < R2)  { if (slot < kNS) sIdx[slot] = i0 + 3; ++slot; }

        count += wtot;
        if (count >= kNS) break;   // block-uniform
    }
    __syncthreads();   // appends visible

    // fill rule: count==0 -> all 0; else pad tail with first in-ball index
    if (count < kNS) {
        int fill = 0;
        if (count > 0) fill = sIdx[0];
        if (t >= count && t < kNS) sIdx[t] = fill;
    }
    __syncthreads();

    // ---- phase 2: gather + write (thread = sample s, channel-group g) ----
    const int s = t & 31;
    const int g = t >> 5;               // 0..7
    const int id = sIdx[s];

    const size_t cs = (size_t)kNP * kNS;
    float* ob = out + ((size_t)b * kOC * kNP + j) * kNS + s;

    if (g == 0) {
        const float g0 = xb[(size_t)id * 3 + 0] - nx;
        const float g1 = xb[(size_t)id * 3 + 1] - ny;
        const float g2 = xb[(size_t)id * 3 + 2] - nz;
        ob[0 * cs] = g0;
        ob[1 * cs] = g1;
        ob[2 * cs] = g2;
    }

    const float* row = tf + ((size_t)b * kN + id) * kC;
    float* obf = ob + 3 * cs;
    #pragma unroll
    for (int mi = 0; mi < 2; ++mi) {
        const int mchunk = g + mi * 8;  // 0..15
        const float4 v = *reinterpret_cast<const float4*>(row + mchunk * 4);
        const size_t c0 = (size_t)mchunk * 4;
        obf[(c0 + 0) * cs] = v.x;
        obf[(c0 + 1) * cs] = v.y;
        obf[(c0 + 2) * cs] = v.z;
        obf[(c0 + 3) * cs] = v.w;
    }
}

// ---------- fallback (R1 kernel): direct gather from (C,N) ----------
__global__ __launch_bounds__(256) void qg_direct(
    const float* __restrict__ xyz, const float* __restrict__ new_xyz,
    const float* __restrict__ feat, float* __restrict__ out)
{
    __shared__ int sIdx[4][kNS];
    const int wave = threadIdx.x >> 6;
    const int lane = threadIdx.x & 63;
    const int bid  = blockIdx.x;
    const int xcd  = bid & 7;
    const int b    = xcd >> 1;
    const int jblk = ((xcd & 1) << 8) | (bid >> 3);
    const int j    = (jblk << 2) | wave;

    const float* __restrict__ xb = xyz + (size_t)b * kN * 3;
    const float* nxp = new_xyz + ((size_t)b * kNP + j) * 3;
    const float nx = nxp[0], ny = nxp[1], nz = nxp[2];
    const float R2 = 0.04f;

    int count = 0;
    for (int base = 0; base < kN; base += 64) {
        const int i = base + lane;
        const float d2 = d2_rn(nx, ny, nz, xb[(size_t)i * 3 + 0],
                               xb[(size_t)i * 3 + 1], xb[(size_t)i * 3 + 2]);
        const bool in = d2 < R2;
        const unsigned long long bal = __ballot(in);
        const int pre  = (int)__popcll(bal & ((1ull << lane) - 1ull));
        const int slot = count + pre;
        if (in && slot < kNS) sIdx[wave][slot] = i;
        count += (int)__popcll(bal);
        if (count >= kNS) break;
    }
    __builtin_amdgcn_wave_barrier();
    if (count == 0) {
        if (lane < kNS) sIdx[wave][lane] = 0;
    } else if (count < kNS) {
        const int first = sIdx[wave][0];
        __builtin_amdgcn_wave_barrier();
        if (lane >= count && lane < kNS) sIdx[wave][lane] = first;
    }
    __builtin_amdgcn_wave_barrier();

    const int s    = lane & 31;
    const int half = lane >> 5;
    const int id   = sIdx[wave][s];
    const float g0 = xb[(size_t)id * 3 + 0] - nx;
    const float g1 = xb[(size_t)id * 3 + 1] - ny;
    const float g2 = xb[(size_t)id * 3 + 2] - nz;
    const size_t cs = (size_t)kNP * kNS;
    float* ob = out + (((size_t)b * kOC) * kNP + j) * kNS + s;
    const float* fb = feat + ((size_t)b * kC) * kN + id;
    #pragma unroll
    for (int cb = 0; cb < kOC; cb += 2) {
        const int c = cb + half;
        if (c < kOC) {
            float v;
            if (c < 3) v = (c == 0) ? g0 : ((c == 1) ? g1 : g2);
            else       v = fb[(size_t)(c - 3) * kN];
            ob[(size_t)c * cs] = v;
        }
    }
}

extern "C" void kernel_launch(void* const* d_in, const int* in_sizes, int n_in,
                              void* d_out, int out_size, void* d_ws, size_t ws_size,
                              hipStream_t stream) {
    const float* xyz     = (const float*)d_in[0];
    const float* new_xyz = (const float*)d_in[1];
    const float* feat    = (const float*)d_in[2];
    float* out           = (float*)d_out;

    const size_t need = (size_t)4 * kN * kC * sizeof(float);  // 16.8 MB
    if (ws_size >= need) {
        float* tf = (float*)d_ws;
        tr_kernel<<<dim3(1024), dim3(256), 0, stream>>>(feat, tf);
        qg_fused <<<dim3(8192), dim3(256), 0, stream>>>(xyz, new_xyz, tf, out);
    } else {
        qg_direct<<<dim3(2048), dim3(256), 0, stream>>>(xyz, new_xyz, feat, out);
    }
}